// Round 2
// baseline (517.664 us; speedup 1.0000x reference)
//
#include <hip/hip_runtime.h>
#include <hip/hip_bf16.h>

#define EPS 1e-6f

constexpr int D  = 160;     // "D" axis (T//S)
constexpr int NN = 82944;   // C*H*W
constexpr int B  = 4;       // batches

typedef __bf16 bf16x8 __attribute__((ext_vector_type(8)));
typedef __bf16 bf16x4 __attribute__((ext_vector_type(4)));
typedef float  floatx4 __attribute__((ext_vector_type(4)));

// ---------------- Kernel A: Gram G[b] = X_b X_b^T (bf16 MFMA, split-K) ----------
constexpr int BK = 64;            // columns per LDS slab
constexpr int BKP = BK + 8;       // 144B row stride -> 4-bank rotation/row, worst 2-way (free)
constexpr int SLABS = 4;          // slabs per block
constexpr int COLS_PER_BLOCK = BK * SLABS;          // 256
constexpr int GRAM_BLOCKS = NN / COLS_PER_BLOCK;    // 324  (x4 batches = 1296 blocks)

__global__ __launch_bounds__(256, 3)   // target 3 blocks/CU (unified regs <= ~168/wave)
void gram_kernel(const float* __restrict__ x, float* __restrict__ G)
{
    __shared__ __align__(16) __bf16 xs[D * BKP];   // 23.04 KB

    const int tid = threadIdx.x;
    const int batch = blockIdx.y;
    const int w  = tid >> 6;        // wave 0..3
    const int l  = tid & 63;
    const int lr = l & 15;          // row/col within 16-tile
    const int lq = l >> 4;          // quad 0..3
    const int itile0 = (w & 1) * 5; // wave's 5 row-tiles
    const int jtile0 = (w >> 1) * 5;// wave's 5 col-tiles
    const int srow = tid >> 4;      // staging: 16 lanes per row
    const int scol = (tid & 15) * 4;

    const float* xb = x + (size_t)batch * D * NN + (size_t)blockIdx.x * COLS_PER_BLOCK;

    floatx4 acc[5][5] = {};

    for (int s = 0; s < SLABS; ++s) {
        const int n0 = s * BK;
        // stage 160 x 64 fp32 -> bf16 LDS (10 passes of 16 rows)
        #pragma unroll
        for (int p = 0; p < 10; ++p) {
            const int d = p * 16 + srow;
            float4 v = *(const float4*)(xb + (size_t)d * NN + n0 + scol);
            bf16x4 h = { (__bf16)v.x, (__bf16)v.y, (__bf16)v.z, (__bf16)v.w };
            *(bf16x4*)&xs[d * BKP + scol] = h;
        }
        __syncthreads();
        #pragma unroll
        for (int k = 0; k < BK / 32; ++k) {
            bf16x8 fa[5], fb[5];
            #pragma unroll
            for (int i = 0; i < 5; ++i) {
                fa[i] = *(const bf16x8*)&xs[((itile0 + i) * 16 + lr) * BKP + k * 32 + lq * 8];
                fb[i] = *(const bf16x8*)&xs[((jtile0 + i) * 16 + lr) * BKP + k * 32 + lq * 8];
            }
            #pragma unroll
            for (int i = 0; i < 5; ++i)
                #pragma unroll
                for (int j = 0; j < 5; ++j)
                    acc[i][j] = __builtin_amdgcn_mfma_f32_16x16x32_bf16(fa[i], fb[j], acc[i][j], 0, 0, 0);
        }
        __syncthreads();
    }

    // epilogue: C/D layout col=lane&15, row=quad*4+reg (any global swap writes G^T == G)
    float* Gb = G + (size_t)batch * D * D;
    #pragma unroll
    for (int i = 0; i < 5; ++i) {
        const int d1base = (itile0 + i) * 16 + lq * 4;
        #pragma unroll
        for (int j = 0; j < 5; ++j) {
            const int d2 = (jtile0 + j) * 16 + lr;
            #pragma unroll
            for (int r = 0; r < 4; ++r)
                atomicAdd(&Gb[(size_t)(d1base + r) * D + d2], acc[i][j][r]);
        }
    }
}

// ---------------- Kernel B: 4-step multiplicative update on G ----------------
__device__ __forceinline__ float block_reduce_bcast(float v, float* red)
{
    #pragma unroll
    for (int off = 32; off > 0; off >>= 1)
        v += __shfl_xor(v, off, 64);
    const int w = threadIdx.x >> 6;
    if ((threadIdx.x & 63) == 0) red[w] = v;
    __syncthreads();
    float s = red[0] + red[1] + red[2] + red[3];
    __syncthreads();
    return s;
}

__global__ __launch_bounds__(256)
void iter_kernel(const float* __restrict__ bases, const float* __restrict__ G,
                 float* __restrict__ bvec, float* __restrict__ svec)
{
    __shared__ float bs[D];
    __shared__ float red[4];
    const int batch = blockIdx.x;
    const int tid = threadIdx.x;
    const float* Gb = G + (size_t)batch * D * D;

    if (tid < D) bs[tid] = bases[batch * D + tid];
    __syncthreads();

    for (int step = 0; step < 4; ++step) {
        float v = (tid < D) ? bs[tid] * bs[tid] : 0.0f;
        const float btb = block_reduce_bcast(v, red);
        const float gamma = btb + EPS;           // exact at step 0 (coef==1); ~1e-6 rel after

        float m = 0.0f;
        if (tid < D) {
            const float* row = Gb + (size_t)tid * D;
            #pragma unroll 8
            for (int j = 0; j < D; j += 4) {
                float4 g4 = *(const float4*)(row + j);
                m += g4.x * bs[j] + g4.y * bs[j + 1] + g4.z * bs[j + 2] + g4.w * bs[j + 3];
            }
        }
        float bm = (tid < D) ? bs[tid] * m : 0.0f;
        const float beta = block_reduce_bcast(bm, red);   // b^T G b
        const float ctc = beta / (gamma * gamma);

        __syncthreads();
        if (tid < D) {
            const float bd = bs[tid];
            bs[tid] = bd * (m / gamma) / (bd * ctc + EPS);  // exact EPS in bases update
        }
        __syncthreads();
    }

    float v = (tid < D) ? bs[tid] * bs[tid] : 0.0f;
    const float btb = block_reduce_bcast(v, red);
    const float inv = 1.0f / (btb + EPS);
    if (tid < D) {
        bvec[batch * D + tid] = bs[tid];
        svec[batch * D + tid] = bs[tid] * inv;
    }
}

// ---------------- Kernel C: t = x^T b4 (fp32), out = (b4/btb4) t^T ----------------
__global__ __launch_bounds__(256)
void out_kernel(const float* __restrict__ x, const float* __restrict__ bvec,
                const float* __restrict__ svec, float* __restrict__ out)
{
    __shared__ float bsh[D], ssh[D];
    __shared__ floatx4 part[256];

    const int tid = threadIdx.x;
    const int batch = blockIdx.y;
    const int g = tid >> 5;          // d-group 0..7
    const int lane = tid & 31;
    const size_t base = (size_t)batch * D * NN + (size_t)blockIdx.x * 128 + lane * 4;

    if (tid < D) { bsh[tid] = bvec[batch * D + tid]; ssh[tid] = svec[batch * D + tid]; }
    __syncthreads();

    floatx4 t = {0.f, 0.f, 0.f, 0.f};
    #pragma unroll
    for (int d = g; d < D; d += 8) {
        floatx4 xv = *(const floatx4*)(x + base + (size_t)d * NN);
        const float bd = bsh[d];
        t += xv * bd;
    }
    part[tid] = t;
    __syncthreads();
    if (tid < 32) {
        floatx4 s = part[lane];
        #pragma unroll
        for (int k = 1; k < 8; ++k)
            s += part[k * 32 + lane];
        part[lane] = s;
    }
    __syncthreads();
    t = part[lane];

    // nontemporal: out is write-once, keep x resident in L3 instead
    #pragma unroll
    for (int d = g; d < D; d += 8) {
        const float sd = ssh[d];
        floatx4 o = t * sd;
        __builtin_nontemporal_store(o, (floatx4*)(out + base + (size_t)d * NN));
    }
}

extern "C" void kernel_launch(void* const* d_in, const int* in_sizes, int n_in,
                              void* d_out, int out_size, void* d_ws, size_t ws_size,
                              hipStream_t stream)
{
    (void)in_sizes; (void)n_in; (void)out_size; (void)ws_size;
    const float* x     = (const float*)d_in[0];
    const float* bases = (const float*)d_in[1];
    float* out = (float*)d_out;

    // G scratch lives in d_out (first 400 KB) -- fully overwritten by out_kernel later.
    float* G    = (float*)d_out;
    float* bvec = (float*)d_ws;          // 4*160 floats
    float* svec = bvec + B * D;          // 4*160 floats

    hipMemsetAsync(G, 0, (size_t)B * D * D * sizeof(float), stream);
    gram_kernel<<<dim3(GRAM_BLOCKS, B), 256, 0, stream>>>(x, G);
    iter_kernel<<<dim3(B), 256, 0, stream>>>(bases, G, bvec, svec);
    out_kernel<<<dim3(NN / 128, B), 256, 0, stream>>>(x, bvec, svec, out);
}

// Round 3
// 448.933 us; speedup vs baseline: 1.1531x; 1.1531x over previous
//
#include <hip/hip_runtime.h>
#include <hip/hip_bf16.h>

#define EPS 1e-6f

constexpr int D  = 160;     // "D" axis (T//S)
constexpr int NN = 82944;   // C*H*W
constexpr int B  = 4;       // batches

typedef __bf16 bf16x8 __attribute__((ext_vector_type(8)));
typedef __bf16 bf16x4 __attribute__((ext_vector_type(4)));
typedef float  floatx4 __attribute__((ext_vector_type(4)));

// ---------------- Kernel A: Gram G[b] = X_b X_b^T (bf16 MFMA, split-K) ----------
// Register-double-buffered: next slab's global loads are issued BEFORE the MFMA
// phase so the memory pipe stays busy during compute (fixes phase-latency bound).
constexpr int BK = 64;            // columns per LDS slab
constexpr int BKP = BK + 8;       // 144B row stride -> worst 2-way LDS aliasing (free)
constexpr int SLABS = 8;          // slabs per block
constexpr int COLS_PER_BLOCK = BK * SLABS;          // 512
constexpr int GRAM_BLOCKS = NN / COLS_PER_BLOCK;    // 162 (x4 batches = 648 blocks)

__global__ __launch_bounds__(256, 2)
void gram_kernel(const float* __restrict__ x, float* __restrict__ G)
{
    __shared__ __align__(16) __bf16 xs[D * BKP];   // 23.04 KB

    const int tid = threadIdx.x;
    const int batch = blockIdx.y;
    const int w  = tid >> 6;        // wave 0..3
    const int l  = tid & 63;
    const int lr = l & 15;          // row/col within 16-tile
    const int lq = l >> 4;          // quad 0..3
    const int itile0 = (w & 1) * 5; // wave's 5 row-tiles
    const int jtile0 = (w >> 1) * 5;// wave's 5 col-tiles
    const int srow = tid >> 4;      // staging: 16 lanes x 4 cols -> 64 cols/row
    const int scol = (tid & 15) * 4;

    const float* xb = x + (size_t)batch * D * NN + (size_t)blockIdx.x * COLS_PER_BLOCK;
    const float* pbase = xb + (size_t)srow * NN + scol;

    floatx4 acc[5][5] = {};
    float4 pf[10];

    // prologue: prefetch slab 0 into registers
    #pragma unroll
    for (int p = 0; p < 10; ++p)
        pf[p] = *(const float4*)(pbase + (size_t)p * 16 * NN);

    for (int s = 0; s < SLABS; ++s) {
        __syncthreads();   // previous compute done reading LDS
        // store phase: convert prefetched fp32 -> bf16 LDS
        #pragma unroll
        for (int p = 0; p < 10; ++p) {
            bf16x4 h = { (__bf16)pf[p].x, (__bf16)pf[p].y, (__bf16)pf[p].z, (__bf16)pf[p].w };
            *(bf16x4*)&xs[(srow + p * 16) * BKP + scol] = h;
        }
        __syncthreads();
        // issue next slab's loads NOW -- they fly during the MFMA phase below
        if (s + 1 < SLABS) {
            const float* pn = pbase + (s + 1) * BK;
            #pragma unroll
            for (int p = 0; p < 10; ++p)
                pf[p] = *(const float4*)(pn + (size_t)p * 16 * NN);
        }
        // compute phase: 2 k-chunks x 25 MFMA
        #pragma unroll
        for (int k = 0; k < BK / 32; ++k) {
            bf16x8 fa[5], fb[5];
            #pragma unroll
            for (int i = 0; i < 5; ++i) {
                fa[i] = *(const bf16x8*)&xs[((itile0 + i) * 16 + lr) * BKP + k * 32 + lq * 8];
                fb[i] = *(const bf16x8*)&xs[((jtile0 + i) * 16 + lr) * BKP + k * 32 + lq * 8];
            }
            #pragma unroll
            for (int i = 0; i < 5; ++i)
                #pragma unroll
                for (int j = 0; j < 5; ++j)
                    acc[i][j] = __builtin_amdgcn_mfma_f32_16x16x32_bf16(fa[i], fb[j], acc[i][j], 0, 0, 0);
        }
    }

    // epilogue: C/D layout col=lane&15, row=quad*4+reg (any global swap writes G^T == G)
    float* Gb = G + (size_t)batch * D * D;
    #pragma unroll
    for (int i = 0; i < 5; ++i) {
        const int d1base = (itile0 + i) * 16 + lq * 4;
        #pragma unroll
        for (int j = 0; j < 5; ++j) {
            const int d2 = (jtile0 + j) * 16 + lr;
            #pragma unroll
            for (int r = 0; r < 4; ++r)
                atomicAdd(&Gb[(size_t)(d1base + r) * D + d2], acc[i][j][r]);
        }
    }
}

// ---------------- Kernel B: 4-step multiplicative update on G ----------------
__device__ __forceinline__ float block_reduce_bcast(float v, float* red)
{
    #pragma unroll
    for (int off = 32; off > 0; off >>= 1)
        v += __shfl_xor(v, off, 64);
    const int w = threadIdx.x >> 6;
    if ((threadIdx.x & 63) == 0) red[w] = v;
    __syncthreads();
    float s = red[0] + red[1] + red[2] + red[3];
    __syncthreads();
    return s;
}

__global__ __launch_bounds__(256)
void iter_kernel(const float* __restrict__ bases, const float* __restrict__ G,
                 float* __restrict__ bvec, float* __restrict__ svec)
{
    __shared__ float bs[D];
    __shared__ float red[4];
    const int batch = blockIdx.x;
    const int tid = threadIdx.x;
    const float* Gb = G + (size_t)batch * D * D;

    if (tid < D) bs[tid] = bases[batch * D + tid];
    __syncthreads();

    for (int step = 0; step < 4; ++step) {
        float v = (tid < D) ? bs[tid] * bs[tid] : 0.0f;
        const float btb = block_reduce_bcast(v, red);
        const float gamma = btb + EPS;           // exact at step 0 (coef==1); ~1e-6 rel after

        float m = 0.0f;
        if (tid < D) {
            const float* row = Gb + (size_t)tid * D;
            #pragma unroll 8
            for (int j = 0; j < D; j += 4) {
                float4 g4 = *(const float4*)(row + j);
                m += g4.x * bs[j] + g4.y * bs[j + 1] + g4.z * bs[j + 2] + g4.w * bs[j + 3];
            }
        }
        float bm = (tid < D) ? bs[tid] * m : 0.0f;
        const float beta = block_reduce_bcast(bm, red);   // b^T G b
        const float ctc = beta / (gamma * gamma);

        __syncthreads();
        if (tid < D) {
            const float bd = bs[tid];
            bs[tid] = bd * (m / gamma) / (bd * ctc + EPS);  // exact EPS in bases update
        }
        __syncthreads();
    }

    float v = (tid < D) ? bs[tid] * bs[tid] : 0.0f;
    const float btb = block_reduce_bcast(v, red);
    const float inv = 1.0f / (btb + EPS);
    if (tid < D) {
        bvec[batch * D + tid] = bs[tid];
        svec[batch * D + tid] = bs[tid] * inv;
    }
}

// ---------------- Kernel C: t = x^T b4 (fp32), out = (b4/btb4) t^T ----------------
// 256 cols/block: 40 independent loads in flight per thread.
__global__ __launch_bounds__(256)
void out_kernel(const float* __restrict__ x, const float* __restrict__ bvec,
                const float* __restrict__ svec, float* __restrict__ out)
{
    __shared__ float bsh[D], ssh[D];
    __shared__ floatx4 partA[256];
    __shared__ floatx4 partB[256];

    const int tid = threadIdx.x;
    const int batch = blockIdx.y;
    const int g = tid >> 5;          // d-group 0..7
    const int lane = tid & 31;
    const size_t base0 = (size_t)batch * D * NN + (size_t)blockIdx.x * 256 + lane * 4;
    const size_t base1 = base0 + 128;

    if (tid < D) { bsh[tid] = bvec[batch * D + tid]; ssh[tid] = svec[batch * D + tid]; }
    __syncthreads();

    floatx4 t0 = {0.f, 0.f, 0.f, 0.f};
    floatx4 t1 = {0.f, 0.f, 0.f, 0.f};
    #pragma unroll
    for (int d = g; d < D; d += 8) {
        floatx4 xv0 = *(const floatx4*)(x + base0 + (size_t)d * NN);
        floatx4 xv1 = *(const floatx4*)(x + base1 + (size_t)d * NN);
        const float bd = bsh[d];
        t0 += xv0 * bd;
        t1 += xv1 * bd;
    }
    partA[tid] = t0;
    partB[tid] = t1;
    __syncthreads();
    if (tid < 32) {
        floatx4 s = partA[tid];
        #pragma unroll
        for (int k = 1; k < 8; ++k) s += partA[k * 32 + tid];
        partA[tid] = s;
    } else if (tid < 64) {
        floatx4 s = partB[tid - 32];
        #pragma unroll
        for (int k = 1; k < 8; ++k) s += partB[k * 32 + (tid - 32)];
        partB[tid - 32] = s;
    }
    __syncthreads();
    t0 = partA[lane];
    t1 = partB[lane];

    // nontemporal: out is write-once, keep x resident in L3 instead
    #pragma unroll
    for (int d = g; d < D; d += 8) {
        const float sd = ssh[d];
        floatx4 o0 = t0 * sd;
        floatx4 o1 = t1 * sd;
        __builtin_nontemporal_store(o0, (floatx4*)(out + base0 + (size_t)d * NN));
        __builtin_nontemporal_store(o1, (floatx4*)(out + base1 + (size_t)d * NN));
    }
}

extern "C" void kernel_launch(void* const* d_in, const int* in_sizes, int n_in,
                              void* d_out, int out_size, void* d_ws, size_t ws_size,
                              hipStream_t stream)
{
    (void)in_sizes; (void)n_in; (void)out_size; (void)ws_size;
    const float* x     = (const float*)d_in[0];
    const float* bases = (const float*)d_in[1];
    float* out = (float*)d_out;

    // G scratch lives in d_out (first 400 KB) -- fully overwritten by out_kernel later.
    float* G    = (float*)d_out;
    float* bvec = (float*)d_ws;          // 4*160 floats
    float* svec = bvec + B * D;          // 4*160 floats

    hipMemsetAsync(G, 0, (size_t)B * D * D * sizeof(float), stream);
    gram_kernel<<<dim3(GRAM_BLOCKS, B), 256, 0, stream>>>(x, G);
    iter_kernel<<<dim3(B), 256, 0, stream>>>(bases, G, bvec, svec);
    out_kernel<<<dim3(NN / 256, B), 256, 0, stream>>>(x, bvec, svec, out);
}